// Round 7
// baseline (347.183 us; speedup 1.0000x reference)
//
#include <hip/hip_runtime.h>
#include <math.h>

#define B_  256
#define H_  200
#define N_  64
#define D_  640
#define DT_ 256
#define NH_ 10
#define HD_ 64
#define MT_ 13   // 13 m-tiles of 16 cover 208 >= 200

typedef __attribute__((ext_vector_type(8))) short bf16x8;
typedef __attribute__((ext_vector_type(4))) float f32x4;

__device__ __forceinline__ float wave_reduce_sum(float v) {
    #pragma unroll
    for (int m = 32; m > 0; m >>= 1) v += __shfl_xor(v, m);
    return v;
}
__device__ __forceinline__ float wave_reduce_max(float v) {
    #pragma unroll
    for (int m = 32; m > 0; m >>= 1) v = fmaxf(v, __shfl_xor(v, m));
    return v;
}
__device__ __forceinline__ float red16_sum(float v) {   // reduce over lane&15 group
    #pragma unroll
    for (int m = 1; m < 16; m <<= 1) v += __shfl_xor(v, m);
    return v;
}
__device__ __forceinline__ float red16_max(float v) {
    #pragma unroll
    for (int m = 1; m < 16; m <<= 1) v = fmaxf(v, __shfl_xor(v, m));
    return v;
}
__device__ __forceinline__ short f2bf(float x) {   // RNE bf16
    unsigned u = __float_as_uint(x);
    unsigned r = (u + 0x7fffu + ((u >> 16) & 1u)) >> 16;
    return (short)r;
}
__device__ __forceinline__ float bf2f(short s) {
    return __uint_as_float(((unsigned)(unsigned short)s) << 16);
}
// LDS XOR swizzle: rows with stride % 128B == 0 spread across banks (bits 4-6)
#define SWZ(row, byte) ((byte) ^ (((row) & 7) << 4))

__global__ __launch_bounds__(256) void convert_w(
    const float* __restrict__ src, short* __restrict__ dst, int n)
{
    for (int i = blockIdx.x * 256 + threadIdx.x; i < n; i += gridDim.x * 256)
        dst[i] = f2bf(src[i]);
}

// Y_bf16[row, d] = bf16( sum_k X[row,k]*W[d,k] + bias[d] );  K = DT_ = 256.
// BM=64 rows/block, 512 threads = 8 waves. Wave w owns cols [w*80, w*80+80),
// all 4 row-tiles. 2-stage register pipeline over kc (explicit prefetch).
__global__ __launch_bounds__(512, 2) void proj_mfma(
    const float* __restrict__ X, const short* __restrict__ Wb,
    const float* __restrict__ bias, short* __restrict__ Y)
{
    __shared__ short A_lds[64 * DT_];   // 32 KB swizzled bf16
    const int t = threadIdx.x;
    const int lane = t & 63, w = t >> 6;
    const int r16 = lane & 15, g = lane >> 4;
    const long row0 = (long)blockIdx.x * 64;

    // stage X -> bf16 LDS: one row per 8 threads, loads batched in regs
    {
        const int srow = t >> 3, sc = t & 7;
        const float4* src = (const float4*)(X + (row0 + srow) * DT_) + sc;
        float4 sv[8];
        #pragma unroll
        for (int j = 0; j < 8; ++j) sv[j] = src[8 * j];
        #pragma unroll
        for (int j = 0; j < 8; ++j) {
            short4 s;
            s.x = f2bf(sv[j].x); s.y = f2bf(sv[j].y);
            s.z = f2bf(sv[j].z); s.w = f2bf(sv[j].w);
            *(short4*)((char*)A_lds + SWZ(srow, srow * (DT_ * 2) + (sc + 8 * j) * 8)) = s;
        }
    }
    __syncthreads();

    f32x4 acc[5][4];
    #pragma unroll
    for (int ct = 0; ct < 5; ++ct)
        #pragma unroll
        for (int rt = 0; rt < 4; ++rt) acc[ct][rt] = (f32x4){0.f,0.f,0.f,0.f};

    const short* Wbase = Wb + (long)(w * 80 + r16) * DT_ + g * 8;

    bf16x8 aA[4], bA[5], aB[4], bB[5];
    #pragma unroll
    for (int rt = 0; rt < 4; ++rt) {
        const int row = rt * 16 + r16;
        aA[rt] = *(const bf16x8*)((const char*)A_lds + SWZ(row, row * (DT_ * 2) + g * 16));
    }
    #pragma unroll
    for (int ct = 0; ct < 5; ++ct) bA[ct] = *(const bf16x8*)(Wbase + ct * 16 * DT_);

    #pragma unroll
    for (int kc = 0; kc < 8; kc += 2) {
        {   // prefetch kc+1 into B set
            const int kn = kc + 1;
            #pragma unroll
            for (int rt = 0; rt < 4; ++rt) {
                const int row = rt * 16 + r16;
                aB[rt] = *(const bf16x8*)((const char*)A_lds +
                          SWZ(row, row * (DT_ * 2) + kn * 64 + g * 16));
            }
            #pragma unroll
            for (int ct = 0; ct < 5; ++ct)
                bB[ct] = *(const bf16x8*)(Wbase + ct * 16 * DT_ + kn * 32);
        }
        #pragma unroll
        for (int ct = 0; ct < 5; ++ct)
            #pragma unroll
            for (int rt = 0; rt < 4; ++rt)
                acc[ct][rt] = __builtin_amdgcn_mfma_f32_16x16x32_bf16(
                                  aA[rt], bA[ct], acc[ct][rt], 0, 0, 0);
        {   // prefetch kc+2 into A set (clamped address on last iter)
            const int kn = (kc + 2 < 8) ? kc + 2 : 0;
            #pragma unroll
            for (int rt = 0; rt < 4; ++rt) {
                const int row = rt * 16 + r16;
                aA[rt] = *(const bf16x8*)((const char*)A_lds +
                          SWZ(row, row * (DT_ * 2) + kn * 64 + g * 16));
            }
            #pragma unroll
            for (int ct = 0; ct < 5; ++ct)
                bA[ct] = *(const bf16x8*)(Wbase + ct * 16 * DT_ + kn * 32);
        }
        #pragma unroll
        for (int ct = 0; ct < 5; ++ct)
            #pragma unroll
            for (int rt = 0; rt < 4; ++rt)
                acc[ct][rt] = __builtin_amdgcn_mfma_f32_16x16x32_bf16(
                                  aB[rt], bB[ct], acc[ct][rt], 0, 0, 0);
    }

    // C/D: out-col = lane&15 (within col-tile), out-row = (lane>>4)*4 + i
    #pragma unroll
    for (int ct = 0; ct < 5; ++ct) {
        const int col = w * 80 + ct * 16 + r16;
        const float bv = bias[col];
        #pragma unroll
        for (int rt = 0; rt < 4; ++rt)
            #pragma unroll
            for (int i = 0; i < 4; ++i)
                Y[(row0 + rt * 16 + g * 4 + i) * (long)D_ + col] =
                    f2bf(acc[ct][rt][i] + bv);
    }
}

// Fused attention + aggregation, one batch b per block.
// 512 threads = 8 waves: wave = (head-half hh 0..1) x (n-tile wm 0..3).
__global__ __launch_bounds__(512, 2) void attn2(
    const short* __restrict__ Qb, const short* __restrict__ Kb,
    float* __restrict__ aw, float* __restrict__ out_tail)
{
    __shared__ float qn_l[N_];
    __shared__ float qw_l[N_];
    __shared__ float aggp[8][MT_ * 16];
    __shared__ float red2[2];
    const int t = threadIdx.x;
    const int lane = t & 63, w = t >> 6;
    const int wm = w & 3, hh = w >> 2;
    const int r16 = lane & 15, g = lane >> 4;
    const int b = blockIdx.x;

    // --- query-norm softmax weights qw[n] (hh==0 waves only) ---
    if (hh == 0) {
        const short* qrow = Qb + ((long)(b * N_ + wm * 16 + r16)) * D_ + g * 160;
        float ss = 0.f;
        #pragma unroll
        for (int j = 0; j < 20; ++j) {
            bf16x8 v = *(const bf16x8*)(qrow + j * 8);
            #pragma unroll
            for (int e = 0; e < 8; ++e) { float f = bf2f(v[e]); ss += f * f; }
        }
        ss += __shfl_xor(ss, 16);
        ss += __shfl_xor(ss, 32);        // reduce over g (4 k-quarters)
        if (g == 0) qn_l[wm * 16 + r16] = ss;
    }
    __syncthreads();
    if (w == 0) {
        float v = sqrtf(qn_l[lane]);
        float mx = wave_reduce_max(v);
        float e = __expf(v - mx);
        float s = wave_reduce_sum(e);
        qw_l[lane] = e / s;
    }
    __syncthreads();

    float qwr[4];
    #pragma unroll
    for (int i = 0; i < 4; ++i) qwr[i] = qw_l[wm * 16 + g * 4 + i];

    const float inv_scale = 0.0395284707521047f;   // 1/sqrt(640)
    float aggl[MT_];
    #pragma unroll
    for (int mt = 0; mt < MT_; ++mt) aggl[mt] = 0.f;

    for (int hi = 0; hi < 5; ++hi) {
        const int h = hh * 5 + hi;
        const short* qbase = Qb + ((long)(b * N_ + wm * 16 + r16)) * D_ + h * HD_ + g * 8;
        bf16x8 a0 = *(const bf16x8*)(qbase);
        bf16x8 a1 = *(const bf16x8*)(qbase + 32);
        // batch ALL K-fragment loads for this head (one L2 round-trip)
        bf16x8 kb0[MT_], kb1[MT_];
        #pragma unroll
        for (int mt = 0; mt < MT_; ++mt) {
            const short* kbase = Kb + ((long)(b * H_ + mt * 16 + r16)) * D_ + h * HD_ + g * 8;
            kb0[mt] = *(const bf16x8*)(kbase);
            kb1[mt] = *(const bf16x8*)(kbase + 32);
        }
        f32x4 acc[MT_];
        #pragma unroll
        for (int mt = 0; mt < MT_; ++mt) {
            f32x4 z = {0.f,0.f,0.f,0.f};
            z = __builtin_amdgcn_mfma_f32_16x16x32_bf16(a0, kb0[mt], z, 0, 0, 0);
            z = __builtin_amdgcn_mfma_f32_16x16x32_bf16(a1, kb1[mt], z, 0, 0, 0);
            acc[mt] = z;
        }
        // softmax over m for rows n = wm*16 + g*4 + i (lane holds col m = mt*16+r16)
        const bool tailok = (r16 < 8);   // mt==12 valid only for m<200
        float mx[4] = {-INFINITY, -INFINITY, -INFINITY, -INFINITY};
        #pragma unroll
        for (int mt = 0; mt < MT_; ++mt) {
            const bool valid = (mt < 12) || tailok;
            #pragma unroll
            for (int i = 0; i < 4; ++i)
                if (valid) mx[i] = fmaxf(mx[i], acc[mt][i]);
        }
        #pragma unroll
        for (int i = 0; i < 4; ++i) mx[i] = red16_max(mx[i]);
        float sum[4] = {0.f, 0.f, 0.f, 0.f};
        #pragma unroll
        for (int mt = 0; mt < MT_; ++mt) {
            const bool valid = (mt < 12) || tailok;
            #pragma unroll
            for (int i = 0; i < 4; ++i) {
                float e = valid ? __expf((acc[mt][i] - mx[i]) * inv_scale) : 0.f;
                acc[mt][i] = e;
                sum[i] += e;
            }
        }
        float fct[4];
        #pragma unroll
        for (int i = 0; i < 4; ++i) fct[i] = qwr[i] / red16_sum(sum[i]);
        #pragma unroll
        for (int mt = 0; mt < MT_; ++mt)
            aggl[mt] += acc[mt][0] * fct[0] + acc[mt][1] * fct[1]
                      + acc[mt][2] * fct[2] + acc[mt][3] * fct[3];
    }
    // reduce over g (row groups) -> wave partial agg for m = mt*16 + r16
    #pragma unroll
    for (int mt = 0; mt < MT_; ++mt) {
        aggl[mt] += __shfl_xor(aggl[mt], 16);
        aggl[mt] += __shfl_xor(aggl[mt], 32);
    }
    if (g == 0) {
        #pragma unroll
        for (int mt = 0; mt < MT_; ++mt) aggp[w][mt * 16 + r16] = aggl[mt];
    }
    __syncthreads();
    if (t < MT_ * 16) {
        float v = 0.f;
        #pragma unroll
        for (int j = 0; j < 8; ++j) v += aggp[j][t];
        aggp[0][t] = v;
    }
    __syncthreads();
    if (w == 0) {
        float v0 = aggp[0][lane], v1 = aggp[0][lane + 64], v2 = aggp[0][lane + 128];
        const bool has3 = lane < (H_ - 192);
        float v3 = has3 ? aggp[0][lane + 192] : -INFINITY;
        float mx = wave_reduce_max(fmaxf(fmaxf(v0, v1), fmaxf(v2, v3)));
        float s = __expf(v0 - mx) + __expf(v1 - mx) + __expf(v2 - mx)
                + (has3 ? __expf(v3 - mx) : 0.f);
        s = wave_reduce_sum(s);
        if (lane == 0) { red2[0] = mx; red2[1] = s; }
    }
    __syncthreads();
    if (t < H_) {
        float v = __expf(aggp[0][t] - red2[0]) / red2[1];
        aw[b * H_ + t] = v;
        out_tail[b * H_ + t] = v;
    }
}

// gate GEMM + blend + LayerNorm, v3. BM=32 rows, 512 threads = 8 waves.
// Wave w owns cols [w*80, w*80+80), 2 row-tiles -> acc[5][2] (40 regs).
// A-operand = UNSCALED clicked bf16 (aw folded into epilogue: z = aw*y + bg).
// Epilogue fully in-register; LN via cross-wave LDS partials. Single clicked
// read; no z round-trip. __launch_bounds__(512,4): cap total regs ~128 ->
// 4 waves/SIMD.
__global__ __launch_bounds__(512, 4) void out_mfma(
    const float* __restrict__ clicked, const float* __restrict__ aw,
    const short* __restrict__ Wgb, const float* __restrict__ bg,
    const float* __restrict__ gamma, const float* __restrict__ beta,
    float* __restrict__ out)
{
    __shared__ short A_lds[32 * D_];      // 40 KB swizzled clicked bf16
    __shared__ float bg_l[D_];
    __shared__ float gm_l[D_];
    __shared__ float bt_l[D_];
    __shared__ float aw_l[32];
    __shared__ float part[32][8][2];      // per-row per-wave partial sums
    __shared__ float mu_l[32], ri_l[32];
    const int t = threadIdx.x;
    const int lane = t & 63, w = t >> 6;
    const int r16 = lane & 15, g = lane >> 4;
    const long row0 = (long)blockIdx.x * 32;

    // stage params
    for (int i = t; i < D_; i += 512) {
        bg_l[i] = bg[i]; gm_l[i] = gamma[i]; bt_l[i] = beta[i];
    }
    if (t < 32) aw_l[t] = aw[row0 + t];

    // stage clicked -> bf16 swizzled LDS (UNSCALED). 16 threads/row, 10 f4 each,
    // in 2 batches of 5 (keeps register peak low but 5 loads in flight).
    {
        const int srow = t >> 4, sc = t & 15;
        const float4* src = (const float4*)(clicked + (row0 + srow) * D_) + sc;
        #pragma unroll
        for (int batch = 0; batch < 2; ++batch) {
            float4 sv[5];
            #pragma unroll
            for (int j = 0; j < 5; ++j) sv[j] = src[16 * (batch * 5 + j)];
            #pragma unroll
            for (int j = 0; j < 5; ++j) {
                const int jj = batch * 5 + j;
                short4 s;
                s.x = f2bf(sv[j].x); s.y = f2bf(sv[j].y);
                s.z = f2bf(sv[j].z); s.w = f2bf(sv[j].w);
                *(short4*)((char*)A_lds +
                    SWZ(srow, srow * (D_ * 2) + (sc + 16 * jj) * 8)) = s;
            }
        }
    }
    __syncthreads();

    f32x4 acc[5][2];
    #pragma unroll
    for (int ct = 0; ct < 5; ++ct) {
        acc[ct][0] = (f32x4){0.f,0.f,0.f,0.f};
        acc[ct][1] = (f32x4){0.f,0.f,0.f,0.f};
    }

    const short* Wbase = Wgb + (long)(w * 80 + r16) * D_ + g * 8;

    bf16x8 bA[5], bB[5];
    #pragma unroll
    for (int ct = 0; ct < 5; ++ct) bA[ct] = *(const bf16x8*)(Wbase + ct * 16 * D_);

    #pragma unroll
    for (int kc = 0; kc < 20; kc += 2) {
        {   // prefetch kc+1 B
            const int kn = kc + 1;
            #pragma unroll
            for (int ct = 0; ct < 5; ++ct)
                bB[ct] = *(const bf16x8*)(Wbase + ct * 16 * D_ + kn * 32);
        }
        {   // compute kc with bA; A frags read JIT from LDS
            bf16x8 a0 = *(const bf16x8*)((const char*)A_lds +
                         SWZ(r16, r16 * (D_ * 2) + kc * 64 + g * 16));
            const int row1 = 16 + r16;
            bf16x8 a1 = *(const bf16x8*)((const char*)A_lds +
                         SWZ(row1, row1 * (D_ * 2) + kc * 64 + g * 16));
            #pragma unroll
            for (int ct = 0; ct < 5; ++ct) {
                acc[ct][0] = __builtin_amdgcn_mfma_f32_16x16x32_bf16(a0, bA[ct], acc[ct][0], 0, 0, 0);
                acc[ct][1] = __builtin_amdgcn_mfma_f32_16x16x32_bf16(a1, bA[ct], acc[ct][1], 0, 0, 0);
            }
        }
        {   // prefetch kc+2 B into bA (clamped on last iter)
            const int kn = (kc + 2 < 20) ? kc + 2 : 0;
            #pragma unroll
            for (int ct = 0; ct < 5; ++ct)
                bA[ct] = *(const bf16x8*)(Wbase + ct * 16 * D_ + kn * 32);
        }
        {   // compute kc+1 with bB
            const int kn = kc + 1;
            bf16x8 a0 = *(const bf16x8*)((const char*)A_lds +
                         SWZ(r16, r16 * (D_ * 2) + kn * 64 + g * 16));
            const int row1 = 16 + r16;
            bf16x8 a1 = *(const bf16x8*)((const char*)A_lds +
                         SWZ(row1, row1 * (D_ * 2) + kn * 64 + g * 16));
            #pragma unroll
            for (int ct = 0; ct < 5; ++ct) {
                acc[ct][0] = __builtin_amdgcn_mfma_f32_16x16x32_bf16(a0, bB[ct], acc[ct][0], 0, 0, 0);
                acc[ct][1] = __builtin_amdgcn_mfma_f32_16x16x32_bf16(a1, bB[ct], acc[ct][1], 0, 0, 0);
            }
        }
    }

    // ---- in-register epilogue: z = aw*y + bg; gate; o = cl*(1 + gt*(aw-1)) ----
    float psum[2][4], psq[2][4];
    #pragma unroll
    for (int rt = 0; rt < 2; ++rt)
        #pragma unroll
        for (int i = 0; i < 4; ++i) { psum[rt][i] = 0.f; psq[rt][i] = 0.f; }

    #pragma unroll
    for (int ct = 0; ct < 5; ++ct) {
        const int col = w * 80 + ct * 16 + r16;
        const float bgv = bg_l[col];
        #pragma unroll
        for (int rt = 0; rt < 2; ++rt)
            #pragma unroll
            for (int i = 0; i < 4; ++i) {
                const int row = rt * 16 + g * 4 + i;
                const float awr = aw_l[row];
                const float cl = bf2f(*(const short*)((const char*)A_lds +
                                   SWZ(row, row * (D_ * 2) + col * 2)));
                const float z  = awr * acc[ct][rt][i] + bgv;
                const float gt = 1.f / (1.f + __expf(-z));
                const float o  = cl * (1.f + gt * (awr - 1.f));
                acc[ct][rt][i] = o;
                psum[rt][i] += o; psq[rt][i] += o * o;
            }
    }
    #pragma unroll
    for (int rt = 0; rt < 2; ++rt)
        #pragma unroll
        for (int i = 0; i < 4; ++i) {
            const float s  = red16_sum(psum[rt][i]);
            const float sq = red16_sum(psq[rt][i]);
            if (r16 == 0) {
                part[rt * 16 + g * 4 + i][w][0] = s;
                part[rt * 16 + g * 4 + i][w][1] = sq;
            }
        }
    __syncthreads();
    if (t < 32) {
        float s = 0.f, q = 0.f;
        #pragma unroll
        for (int j = 0; j < 8; ++j) { s += part[t][j][0]; q += part[t][j][1]; }
        const float m = s * (1.f / D_);
        const float v = q * (1.f / D_) - m * m;
        mu_l[t] = m;
        ri_l[t] = 1.0f / sqrtf(v + 1e-5f);
    }
    __syncthreads();

    #pragma unroll
    for (int ct = 0; ct < 5; ++ct) {
        const int col = w * 80 + ct * 16 + r16;
        const float gmv = gm_l[col], btv = bt_l[col];
        #pragma unroll
        for (int rt = 0; rt < 2; ++rt)
            #pragma unroll
            for (int i = 0; i < 4; ++i) {
                const int row = rt * 16 + g * 4 + i;
                out[(row0 + row) * (long)D_ + col] =
                    (acc[ct][rt][i] - mu_l[row]) * ri_l[row] * gmv + btv;
            }
    }
}

extern "C" void kernel_launch(void* const* d_in, const int* in_sizes, int n_in,
                              void* d_out, int out_size, void* d_ws, size_t ws_size,
                              hipStream_t stream) {
    const float* clicked_news   = (const float*)d_in[0];   // [B,H,D]
    const float* clicked_topics = (const float*)d_in[1];   // [B,H,Dt]
    const float* cand_topics    = (const float*)d_in[2];   // [B,N,Dt]
    const float* Wq = (const float*)d_in[3];
    const float* bq = (const float*)d_in[4];
    const float* Wk = (const float*)d_in[5];
    const float* bk = (const float*)d_in[6];
    // d_in[7], d_in[8] = Wv, bv: dead code w.r.t. outputs
    const float* Wg = (const float*)d_in[9];
    const float* bg = (const float*)d_in[10];
    const float* ln_gamma = (const float*)d_in[11];
    const float* ln_beta  = (const float*)d_in[12];

    float* out = (float*)d_out;
    float* ws  = (float*)d_ws;

    // ws layout: aw (f32), then bf16 arrays
    float* aw = ws;                                     // B*H floats
    short* sbase = (short*)(ws + (long)B_ * H_);
    short* Qb   = sbase;                                // B*N*D  = 10,485,760
    short* Wq_b = Qb + (long)B_ * N_ * D_;              // 163,840
    short* Wg_b = Wq_b + (long)D_ * DT_;                // 409,600
    short* Wk_b = Wg_b + (long)D_ * D_;                 // 163,840
    // Kb (bf16) lives at the start of d_out: read by attn2, then overwritten
    // by out_mfma's final output. Padded by 8 rows for the mt=12 tail reads.
    short* Kb = (short*)d_out;                          // (B*H + 8) * D_ shorts
    float* out_tail = out + (long)B_ * H_ * D_;         // attn_weights_agg

    convert_w<<<128, 256, 0, stream>>>(Wq, Wq_b, D_ * DT_);
    convert_w<<<128, 256, 0, stream>>>(Wk, Wk_b, D_ * DT_);
    convert_w<<<256, 256, 0, stream>>>(Wg, Wg_b, D_ * D_);

    proj_mfma<<<(B_ * N_) / 64, 512, 0, stream>>>(cand_topics, Wq_b, bq, Qb);
    proj_mfma<<<(B_ * H_) / 64, 512, 0, stream>>>(clicked_topics, Wk_b, bk, Kb);
    attn2<<<B_, 512, 0, stream>>>(Qb, Kb, aw, out_tail);
    out_mfma<<<(B_ * H_) / 32, 512, 0, stream>>>(clicked_news, aw, Wg_b, bg,
                                                 ln_gamma, ln_beta, out);
}

// Round 8
// 316.485 us; speedup vs baseline: 1.0970x; 1.0970x over previous
//
#include <hip/hip_runtime.h>
#include <math.h>

#define B_  256
#define H_  200
#define N_  64
#define D_  640
#define DT_ 256
#define NH_ 10
#define HD_ 64
#define MT_ 13   // 13 m-tiles of 16 cover 208 >= 200

typedef __attribute__((ext_vector_type(8))) short bf16x8;
typedef __attribute__((ext_vector_type(4))) float f32x4;

__device__ __forceinline__ float wave_reduce_sum(float v) {
    #pragma unroll
    for (int m = 32; m > 0; m >>= 1) v += __shfl_xor(v, m);
    return v;
}
__device__ __forceinline__ float wave_reduce_max(float v) {
    #pragma unroll
    for (int m = 32; m > 0; m >>= 1) v = fmaxf(v, __shfl_xor(v, m));
    return v;
}
__device__ __forceinline__ float red16_sum(float v) {   // reduce over lane&15 group
    #pragma unroll
    for (int m = 1; m < 16; m <<= 1) v += __shfl_xor(v, m);
    return v;
}
__device__ __forceinline__ float red16_max(float v) {
    #pragma unroll
    for (int m = 1; m < 16; m <<= 1) v = fmaxf(v, __shfl_xor(v, m));
    return v;
}
__device__ __forceinline__ short f2bf(float x) {   // RNE bf16
    unsigned u = __float_as_uint(x);
    unsigned r = (u + 0x7fffu + ((u >> 16) & 1u)) >> 16;
    return (short)r;
}
__device__ __forceinline__ float bf2f(short s) {
    return __uint_as_float(((unsigned)(unsigned short)s) << 16);
}
// LDS XOR swizzle for A (row stride 1280B): spread rows across banks
#define SWZ(row, byte) ((byte) ^ (((row) & 7) << 4))
// W-chunk swizzle (col stride 64B): short-index XOR
#define WSWZ_S(col, sidx) ((sidx) ^ ((((col) >> 1) & 3) << 3))

__device__ __forceinline__ void gload_lds16(const void* g, void* lds) {
    __builtin_amdgcn_global_load_lds(
        (const __attribute__((address_space(1))) void*)g,
        (__attribute__((address_space(3))) void*)lds, 16, 0, 0);
}

__global__ __launch_bounds__(256) void convert_w(
    const float* __restrict__ src, short* __restrict__ dst, int n)
{
    for (int i = blockIdx.x * 256 + threadIdx.x; i < n; i += gridDim.x * 256)
        dst[i] = f2bf(src[i]);
}

// Gate weight -> bf16 in CHUNKED+PRE-SWIZZLED layout:
// dst[kc][ WSWZ_S(col, col*32+kk) ] = Wg[col][kc*32+kk]
// so that out_mfma's LINEAR global_load_lds produces a bank-friendly W_lds.
__global__ __launch_bounds__(256) void convert_wg(
    const float* __restrict__ src, short* __restrict__ dst)
{
    for (int i = blockIdx.x * 256 + threadIdx.x; i < D_ * D_; i += gridDim.x * 256) {
        const int col = i / D_, k = i % D_;
        const int kc = k >> 5, kk = k & 31;
        dst[kc * (D_ * 32) + WSWZ_S(col, col * 32 + kk)] = f2bf(src[i]);
    }
}

// Y_bf16[row, d] = bf16( sum_k X[row,k]*W[d,k] + bias[d] );  K = DT_ = 256.
// BM=64 rows/block, 512 threads = 8 waves. Wave w owns cols [w*80, w*80+80),
// all 4 row-tiles. 2-stage register pipeline over kc (explicit prefetch).
__global__ __launch_bounds__(512, 2) void proj_mfma(
    const float* __restrict__ X, const short* __restrict__ Wb,
    const float* __restrict__ bias, short* __restrict__ Y)
{
    __shared__ short A_lds[64 * DT_];   // 32 KB swizzled bf16
    const int t = threadIdx.x;
    const int lane = t & 63, w = t >> 6;
    const int r16 = lane & 15, g = lane >> 4;
    const long row0 = (long)blockIdx.x * 64;

    // stage X -> bf16 LDS: one row per 8 threads, loads batched in regs
    {
        const int srow = t >> 3, sc = t & 7;
        const float4* src = (const float4*)(X + (row0 + srow) * DT_) + sc;
        float4 sv[8];
        #pragma unroll
        for (int j = 0; j < 8; ++j) sv[j] = src[8 * j];
        #pragma unroll
        for (int j = 0; j < 8; ++j) {
            short4 s;
            s.x = f2bf(sv[j].x); s.y = f2bf(sv[j].y);
            s.z = f2bf(sv[j].z); s.w = f2bf(sv[j].w);
            *(short4*)((char*)A_lds + SWZ(srow, srow * (DT_ * 2) + (sc + 8 * j) * 8)) = s;
        }
    }
    __syncthreads();

    f32x4 acc[5][4];
    #pragma unroll
    for (int ct = 0; ct < 5; ++ct)
        #pragma unroll
        for (int rt = 0; rt < 4; ++rt) acc[ct][rt] = (f32x4){0.f,0.f,0.f,0.f};

    const short* Wbase = Wb + (long)(w * 80 + r16) * DT_ + g * 8;

    bf16x8 aA[4], bA[5], aB[4], bB[5];
    #pragma unroll
    for (int rt = 0; rt < 4; ++rt) {
        const int row = rt * 16 + r16;
        aA[rt] = *(const bf16x8*)((const char*)A_lds + SWZ(row, row * (DT_ * 2) + g * 16));
    }
    #pragma unroll
    for (int ct = 0; ct < 5; ++ct) bA[ct] = *(const bf16x8*)(Wbase + ct * 16 * DT_);

    #pragma unroll
    for (int kc = 0; kc < 8; kc += 2) {
        {   // prefetch kc+1 into B set
            const int kn = kc + 1;
            #pragma unroll
            for (int rt = 0; rt < 4; ++rt) {
                const int row = rt * 16 + r16;
                aB[rt] = *(const bf16x8*)((const char*)A_lds +
                          SWZ(row, row * (DT_ * 2) + kn * 64 + g * 16));
            }
            #pragma unroll
            for (int ct = 0; ct < 5; ++ct)
                bB[ct] = *(const bf16x8*)(Wbase + ct * 16 * DT_ + kn * 32);
        }
        #pragma unroll
        for (int ct = 0; ct < 5; ++ct)
            #pragma unroll
            for (int rt = 0; rt < 4; ++rt)
                acc[ct][rt] = __builtin_amdgcn_mfma_f32_16x16x32_bf16(
                                  aA[rt], bA[ct], acc[ct][rt], 0, 0, 0);
        {   // prefetch kc+2 into A set (clamped address on last iter)
            const int kn = (kc + 2 < 8) ? kc + 2 : 0;
            #pragma unroll
            for (int rt = 0; rt < 4; ++rt) {
                const int row = rt * 16 + r16;
                aA[rt] = *(const bf16x8*)((const char*)A_lds +
                          SWZ(row, row * (DT_ * 2) + kn * 64 + g * 16));
            }
            #pragma unroll
            for (int ct = 0; ct < 5; ++ct)
                bA[ct] = *(const bf16x8*)(Wbase + ct * 16 * DT_ + kn * 32);
        }
        #pragma unroll
        for (int ct = 0; ct < 5; ++ct)
            #pragma unroll
            for (int rt = 0; rt < 4; ++rt)
                acc[ct][rt] = __builtin_amdgcn_mfma_f32_16x16x32_bf16(
                                  aB[rt], bB[ct], acc[ct][rt], 0, 0, 0);
    }

    // C/D: out-col = lane&15 (within col-tile), out-row = (lane>>4)*4 + i
    #pragma unroll
    for (int ct = 0; ct < 5; ++ct) {
        const int col = w * 80 + ct * 16 + r16;
        const float bv = bias[col];
        #pragma unroll
        for (int rt = 0; rt < 4; ++rt)
            #pragma unroll
            for (int i = 0; i < 4; ++i)
                Y[(row0 + rt * 16 + g * 4 + i) * (long)D_ + col] =
                    f2bf(acc[ct][rt][i] + bv);
    }
}

// Fused attention + aggregation, one batch b per block.
// 512 threads = 8 waves: wave = (head-half hh 0..1) x (n-tile wm 0..3).
__global__ __launch_bounds__(512, 2) void attn2(
    const short* __restrict__ Qb, const short* __restrict__ Kb,
    float* __restrict__ aw, float* __restrict__ out_tail)
{
    __shared__ float qn_l[N_];
    __shared__ float qw_l[N_];
    __shared__ float aggp[8][MT_ * 16];
    __shared__ float red2[2];
    const int t = threadIdx.x;
    const int lane = t & 63, w = t >> 6;
    const int wm = w & 3, hh = w >> 2;
    const int r16 = lane & 15, g = lane >> 4;
    const int b = blockIdx.x;

    // --- query-norm softmax weights qw[n] (hh==0 waves only) ---
    if (hh == 0) {
        const short* qrow = Qb + ((long)(b * N_ + wm * 16 + r16)) * D_ + g * 160;
        float ss = 0.f;
        #pragma unroll
        for (int j = 0; j < 20; ++j) {
            bf16x8 v = *(const bf16x8*)(qrow + j * 8);
            #pragma unroll
            for (int e = 0; e < 8; ++e) { float f = bf2f(v[e]); ss += f * f; }
        }
        ss += __shfl_xor(ss, 16);
        ss += __shfl_xor(ss, 32);        // reduce over g (4 k-quarters)
        if (g == 0) qn_l[wm * 16 + r16] = ss;
    }
    __syncthreads();
    if (w == 0) {
        float v = sqrtf(qn_l[lane]);
        float mx = wave_reduce_max(v);
        float e = __expf(v - mx);
        float s = wave_reduce_sum(e);
        qw_l[lane] = e / s;
    }
    __syncthreads();

    float qwr[4];
    #pragma unroll
    for (int i = 0; i < 4; ++i) qwr[i] = qw_l[wm * 16 + g * 4 + i];

    const float inv_scale = 0.0395284707521047f;   // 1/sqrt(640)
    float aggl[MT_];
    #pragma unroll
    for (int mt = 0; mt < MT_; ++mt) aggl[mt] = 0.f;

    for (int hi = 0; hi < 5; ++hi) {
        const int h = hh * 5 + hi;
        const short* qbase = Qb + ((long)(b * N_ + wm * 16 + r16)) * D_ + h * HD_ + g * 8;
        bf16x8 a0 = *(const bf16x8*)(qbase);
        bf16x8 a1 = *(const bf16x8*)(qbase + 32);
        // batch ALL K-fragment loads for this head (one L2 round-trip)
        bf16x8 kb0[MT_], kb1[MT_];
        #pragma unroll
        for (int mt = 0; mt < MT_; ++mt) {
            const short* kbase = Kb + ((long)(b * H_ + mt * 16 + r16)) * D_ + h * HD_ + g * 8;
            kb0[mt] = *(const bf16x8*)(kbase);
            kb1[mt] = *(const bf16x8*)(kbase + 32);
        }
        f32x4 acc[MT_];
        #pragma unroll
        for (int mt = 0; mt < MT_; ++mt) {
            f32x4 z = {0.f,0.f,0.f,0.f};
            z = __builtin_amdgcn_mfma_f32_16x16x32_bf16(a0, kb0[mt], z, 0, 0, 0);
            z = __builtin_amdgcn_mfma_f32_16x16x32_bf16(a1, kb1[mt], z, 0, 0, 0);
            acc[mt] = z;
        }
        // softmax over m for rows n = wm*16 + g*4 + i (lane holds col m = mt*16+r16)
        const bool tailok = (r16 < 8);   // mt==12 valid only for m<200
        float mx[4] = {-INFINITY, -INFINITY, -INFINITY, -INFINITY};
        #pragma unroll
        for (int mt = 0; mt < MT_; ++mt) {
            const bool valid = (mt < 12) || tailok;
            #pragma unroll
            for (int i = 0; i < 4; ++i)
                if (valid) mx[i] = fmaxf(mx[i], acc[mt][i]);
        }
        #pragma unroll
        for (int i = 0; i < 4; ++i) mx[i] = red16_max(mx[i]);
        float sum[4] = {0.f, 0.f, 0.f, 0.f};
        #pragma unroll
        for (int mt = 0; mt < MT_; ++mt) {
            const bool valid = (mt < 12) || tailok;
            #pragma unroll
            for (int i = 0; i < 4; ++i) {
                float e = valid ? __expf((acc[mt][i] - mx[i]) * inv_scale) : 0.f;
                acc[mt][i] = e;
                sum[i] += e;
            }
        }
        float fct[4];
        #pragma unroll
        for (int i = 0; i < 4; ++i) fct[i] = qwr[i] / red16_sum(sum[i]);
        #pragma unroll
        for (int mt = 0; mt < MT_; ++mt)
            aggl[mt] += acc[mt][0] * fct[0] + acc[mt][1] * fct[1]
                      + acc[mt][2] * fct[2] + acc[mt][3] * fct[3];
    }
    // reduce over g (row groups) -> wave partial agg for m = mt*16 + r16
    #pragma unroll
    for (int mt = 0; mt < MT_; ++mt) {
        aggl[mt] += __shfl_xor(aggl[mt], 16);
        aggl[mt] += __shfl_xor(aggl[mt], 32);
    }
    if (g == 0) {
        #pragma unroll
        for (int mt = 0; mt < MT_; ++mt) aggp[w][mt * 16 + r16] = aggl[mt];
    }
    __syncthreads();
    if (t < MT_ * 16) {
        float v = 0.f;
        #pragma unroll
        for (int j = 0; j < 8; ++j) v += aggp[j][t];
        aggp[0][t] = v;
    }
    __syncthreads();
    if (w == 0) {
        float v0 = aggp[0][lane], v1 = aggp[0][lane + 64], v2 = aggp[0][lane + 128];
        const bool has3 = lane < (H_ - 192);
        float v3 = has3 ? aggp[0][lane + 192] : -INFINITY;
        float mx = wave_reduce_max(fmaxf(fmaxf(v0, v1), fmaxf(v2, v3)));
        float s = __expf(v0 - mx) + __expf(v1 - mx) + __expf(v2 - mx)
                + (has3 ? __expf(v3 - mx) : 0.f);
        s = wave_reduce_sum(s);
        if (lane == 0) { red2[0] = mx; red2[1] = s; }
    }
    __syncthreads();
    if (t < H_) {
        float v = __expf(aggp[0][t] - red2[0]) / red2[1];
        aw[b * H_ + t] = v;
        out_tail[b * H_ + t] = v;
    }
}

// gate GEMM + blend + LayerNorm, v4: streaming-LDS GEMM.
// BM=64, 512 threads = 8 waves; K chunked at KC=32 (20 chunks).
// W-chunk [640 cols][32 k] staged per chunk via global_load_lds from the
// pre-swizzled Wg_b (linear dest, swizzled read). A (clicked) staged per
// chunk (1 float4/thread, one-chunk register prefetch) into the full
// A_lds[64][640] so the fused blend+LN epilogue has cl on-chip.
__global__ __launch_bounds__(512, 2) void out_mfma(
    const float* __restrict__ clicked, const float* __restrict__ aw,
    const short* __restrict__ Wgb, const float* __restrict__ bg,
    const float* __restrict__ gamma, const float* __restrict__ beta,
    float* __restrict__ out)
{
    __shared__ short A_lds[64 * D_];      // 80 KB swizzled clicked bf16
    __shared__ short W_lds[D_ * 32];      // 40 KB W-chunk (pre-swizzled layout)
    __shared__ float aw_l[64];
    __shared__ float part[64][8][2];      // per-row per-wave LN partials
    __shared__ float mu_l[64], ri_l[64];
    const int t = threadIdx.x;
    const int lane = t & 63, w = t >> 6;
    const int r16 = lane & 15, g = lane >> 4;
    const long row0 = (long)blockIdx.x * 64;

    if (t < 64) aw_l[t] = aw[row0 + t];

    // per-thread epilogue params (cols w*80 + ct*16 + r16)
    float bgr[5], gmr[5], btr[5];
    #pragma unroll
    for (int ct = 0; ct < 5; ++ct) {
        const int col = w * 80 + ct * 16 + r16;
        bgr[ct] = bg[col]; gmr[ct] = gamma[col]; btr[ct] = beta[col];
    }

    // A-chunk addressing: thread -> (row = t>>3, kseg = t&7)
    const int arow = t >> 3, aseg = t & 7;
    const float4* Abase = (const float4*)(clicked + (row0 + arow) * D_);

    f32x4 acc[5][4];
    #pragma unroll
    for (int ct = 0; ct < 5; ++ct)
        #pragma unroll
        for (int rt = 0; rt < 4; ++rt) acc[ct][rt] = (f32x4){0.f,0.f,0.f,0.f};

    float4 av = Abase[aseg];   // prefetch A chunk 0

    for (int kc = 0; kc < 20; ++kc) {
        // stage W-chunk kc: 2560 x 16B, linear global_load_lds
        {
            const short* wsrc = Wgb + (long)kc * (D_ * 32);
            #pragma unroll
            for (int j = 0; j < 5; ++j) {
                const int c16 = t + j * 512;
                gload_lds16(wsrc + c16 * 8, (char*)W_lds + c16 * 16);
            }
        }
        // write prefetched A chunk kc into A_lds
        {
            short4 s;
            s.x = f2bf(av.x); s.y = f2bf(av.y); s.z = f2bf(av.z); s.w = f2bf(av.w);
            *(short4*)((char*)A_lds +
                SWZ(arow, arow * (D_ * 2) + kc * 64 + aseg * 8)) = s;
        }
        __syncthreads();   // drains global_load_lds + ds_writes

        // prefetch A chunk kc+1 (overlaps MFMAs; drained at next barrier)
        {
            const int kn = (kc + 1 < 20) ? kc + 1 : 0;
            av = Abase[kn * 8 + aseg];
        }

        // compute: 20 MFMAs on chunk kc
        bf16x8 bb[5];
        #pragma unroll
        for (int ct = 0; ct < 5; ++ct) {
            const int col = w * 80 + ct * 16 + r16;
            bb[ct] = *(const bf16x8*)(W_lds + WSWZ_S(col, col * 32 + g * 8));
        }
        bf16x8 a[4];
        #pragma unroll
        for (int rt = 0; rt < 4; ++rt) {
            const int row = rt * 16 + r16;
            a[rt] = *(const bf16x8*)((const char*)A_lds +
                     SWZ(row, row * (D_ * 2) + kc * 64 + g * 16));
        }
        #pragma unroll
        for (int ct = 0; ct < 5; ++ct)
            #pragma unroll
            for (int rt = 0; rt < 4; ++rt)
                acc[ct][rt] = __builtin_amdgcn_mfma_f32_16x16x32_bf16(
                                  a[rt], bb[ct], acc[ct][rt], 0, 0, 0);
        __syncthreads();   // W_lds safe to overwrite next chunk
    }

    // ---- in-register epilogue: z = aw*y + bg; gate; o = cl*(1 + gt*(aw-1)) ----
    float psum[4][2], psq[4][2];
    #pragma unroll
    for (int i = 0; i < 4; ++i)
        #pragma unroll
        for (int rt2 = 0; rt2 < 2; ++rt2) { psum[i][rt2] = 0.f; psq[i][rt2] = 0.f; }
    // note: need per-row accumulators for 4 row-tiles x 4 i -> fold rt into two
    // groups to keep register count low? No -- keep full [4][4].
    float ps[4][4], pq[4][4];
    #pragma unroll
    for (int rt = 0; rt < 4; ++rt)
        #pragma unroll
        for (int i = 0; i < 4; ++i) { ps[rt][i] = 0.f; pq[rt][i] = 0.f; }

    #pragma unroll
    for (int ct = 0; ct < 5; ++ct) {
        const int col = w * 80 + ct * 16 + r16;
        const float bgv = bgr[ct];
        #pragma unroll
        for (int rt = 0; rt < 4; ++rt)
            #pragma unroll
            for (int i = 0; i < 4; ++i) {
                const int row = rt * 16 + g * 4 + i;
                const float awr = aw_l[row];
                const float cl = bf2f(*(const short*)((const char*)A_lds +
                                   SWZ(row, row * (D_ * 2) + col * 2)));
                const float z  = awr * acc[ct][rt][i] + bgv;
                const float gt = 1.f / (1.f + __expf(-z));
                const float o  = cl * (1.f + gt * (awr - 1.f));
                acc[ct][rt][i] = o;
                ps[rt][i] += o; pq[rt][i] += o * o;
            }
    }
    #pragma unroll
    for (int rt = 0; rt < 4; ++rt)
        #pragma unroll
        for (int i = 0; i < 4; ++i) {
            const float s  = red16_sum(ps[rt][i]);
            const float sq = red16_sum(pq[rt][i]);
            if (r16 == 0) {
                part[rt * 16 + g * 4 + i][w][0] = s;
                part[rt * 16 + g * 4 + i][w][1] = sq;
            }
        }
    __syncthreads();
    if (t < 64) {
        float s = 0.f, q = 0.f;
        #pragma unroll
        for (int j = 0; j < 8; ++j) { s += part[t][j][0]; q += part[t][j][1]; }
        const float m = s * (1.f / D_);
        const float v = q * (1.f / D_) - m * m;
        mu_l[t] = m;
        ri_l[t] = 1.0f / sqrtf(v + 1e-5f);
    }
    __syncthreads();

    #pragma unroll
    for (int ct = 0; ct < 5; ++ct) {
        const int col = w * 80 + ct * 16 + r16;
        const float gmv = gmr[ct], btv = btr[ct];
        #pragma unroll
        for (int rt = 0; rt < 4; ++rt)
            #pragma unroll
            for (int i = 0; i < 4; ++i) {
                const int row = rt * 16 + g * 4 + i;
                out[(row0 + row) * (long)D_ + col] =
                    (acc[ct][rt][i] - mu_l[row]) * ri_l[row] * gmv + btv;
            }
    }
}

extern "C" void kernel_launch(void* const* d_in, const int* in_sizes, int n_in,
                              void* d_out, int out_size, void* d_ws, size_t ws_size,
                              hipStream_t stream) {
    const float* clicked_news   = (const float*)d_in[0];   // [B,H,D]
    const float* clicked_topics = (const float*)d_in[1];   // [B,H,Dt]
    const float* cand_topics    = (const float*)d_in[2];   // [B,N,Dt]
    const float* Wq = (const float*)d_in[3];
    const float* bq = (const float*)d_in[4];
    const float* Wk = (const float*)d_in[5];
    const float* bk = (const float*)d_in[6];
    // d_in[7], d_in[8] = Wv, bv: dead code w.r.t. outputs
    const float* Wg = (const float*)d_in[9];
    const float* bg = (const float*)d_in[10];
    const float* ln_gamma = (const float*)d_in[11];
    const float* ln_beta  = (const float*)d_in[12];

    float* out = (float*)d_out;
    float* ws  = (float*)d_ws;

    // ws layout: aw (f32), then bf16 arrays
    float* aw = ws;                                     // B*H floats
    short* sbase = (short*)(ws + (long)B_ * H_);
    short* Qb   = sbase;                                // B*N*D  = 10,485,760
    short* Wq_b = Qb + (long)B_ * N_ * D_;              // 163,840
    short* Wg_b = Wq_b + (long)D_ * DT_;                // 409,600 (chunked+swizzled)
    short* Wk_b = Wg_b + (long)D_ * D_;                 // 163,840
    // Kb (bf16) lives at the start of d_out: read by attn2, then overwritten
    // by out_mfma's final output. Padded by 8 rows for the mt=12 tail reads.
    short* Kb = (short*)d_out;                          // (B*H + 8) * D_ shorts
    float* out_tail = out + (long)B_ * H_ * D_;         // attn_weights_agg

    convert_w<<<128, 256, 0, stream>>>(Wq, Wq_b, D_ * DT_);
    convert_w<<<128, 256, 0, stream>>>(Wk, Wk_b, D_ * DT_);
    convert_wg<<<256, 256, 0, stream>>>(Wg, Wg_b);

    proj_mfma<<<(B_ * N_) / 64, 512, 0, stream>>>(cand_topics, Wq_b, bq, Qb);
    proj_mfma<<<(B_ * H_) / 64, 512, 0, stream>>>(clicked_topics, Wk_b, bk, Kb);
    attn2<<<B_, 512, 0, stream>>>(Qb, Kb, aw, out_tail);
    out_mfma<<<(B_ * H_) / 64, 512, 0, stream>>>(clicked_news, aw, Wg_b, bg,
                                                 ln_gamma, ln_beta, out);
}

// Round 9
// 299.321 us; speedup vs baseline: 1.1599x; 1.0573x over previous
//
#include <hip/hip_runtime.h>
#include <math.h>

#define B_  256
#define H_  200
#define N_  64
#define D_  640
#define DT_ 256
#define NH_ 10
#define HD_ 64
#define MT_ 13   // 13 m-tiles of 16 cover 208 >= 200

typedef __attribute__((ext_vector_type(8))) short bf16x8;
typedef __attribute__((ext_vector_type(4))) float f32x4;

__device__ __forceinline__ float wave_reduce_sum(float v) {
    #pragma unroll
    for (int m = 32; m > 0; m >>= 1) v += __shfl_xor(v, m);
    return v;
}
__device__ __forceinline__ float wave_reduce_max(float v) {
    #pragma unroll
    for (int m = 32; m > 0; m >>= 1) v = fmaxf(v, __shfl_xor(v, m));
    return v;
}
__device__ __forceinline__ float red16_sum(float v) {   // reduce over lane&15 group
    #pragma unroll
    for (int m = 1; m < 16; m <<= 1) v += __shfl_xor(v, m);
    return v;
}
__device__ __forceinline__ float red16_max(float v) {
    #pragma unroll
    for (int m = 1; m < 16; m <<= 1) v = fmaxf(v, __shfl_xor(v, m));
    return v;
}
__device__ __forceinline__ short f2bf(float x) {   // RNE bf16
    unsigned u = __float_as_uint(x);
    unsigned r = (u + 0x7fffu + ((u >> 16) & 1u)) >> 16;
    return (short)r;
}
__device__ __forceinline__ float bf2f(short s) {
    return __uint_as_float(((unsigned)(unsigned short)s) << 16);
}
// LDS XOR swizzle for A (row stride 1280B): spread rows across banks
#define SWZ(row, byte) ((byte) ^ (((row) & 7) << 4))
// W-chunk swizzle (col stride 64B): short-index XOR
#define WSWZ_S(col, sidx) ((sidx) ^ ((((col) >> 1) & 3) << 3))

__device__ __forceinline__ void gload_lds16(const void* g, void* lds) {
    __builtin_amdgcn_global_load_lds(
        (const __attribute__((address_space(1))) void*)g,
        (__attribute__((address_space(3))) void*)lds, 16, 0, 0);
}

__global__ __launch_bounds__(256) void convert_w(
    const float* __restrict__ src, short* __restrict__ dst, int n)
{
    for (int i = blockIdx.x * 256 + threadIdx.x; i < n; i += gridDim.x * 256)
        dst[i] = f2bf(src[i]);
}

// Gate weight -> bf16 in CHUNKED+PRE-SWIZZLED layout:
// dst[kc][ WSWZ_S(col, col*32+kk) ] = Wg[col][kc*32+kk]
__global__ __launch_bounds__(256) void convert_wg(
    const float* __restrict__ src, short* __restrict__ dst)
{
    for (int i = blockIdx.x * 256 + threadIdx.x; i < D_ * D_; i += gridDim.x * 256) {
        const int col = i / D_, k = i % D_;
        const int kc = k >> 5, kk = k & 31;
        dst[kc * (D_ * 32) + WSWZ_S(col, col * 32 + kk)] = f2bf(src[i]);
    }
}

// Y_bf16[row, d] = bf16( sum_k X[row,k]*W[d,k] + bias[d] );  K = DT_ = 256.
__global__ __launch_bounds__(512, 2) void proj_mfma(
    const float* __restrict__ X, const short* __restrict__ Wb,
    const float* __restrict__ bias, short* __restrict__ Y)
{
    __shared__ short A_lds[64 * DT_];   // 32 KB swizzled bf16
    const int t = threadIdx.x;
    const int lane = t & 63, w = t >> 6;
    const int r16 = lane & 15, g = lane >> 4;
    const long row0 = (long)blockIdx.x * 64;

    {
        const int srow = t >> 3, sc = t & 7;
        const float4* src = (const float4*)(X + (row0 + srow) * DT_) + sc;
        float4 sv[8];
        #pragma unroll
        for (int j = 0; j < 8; ++j) sv[j] = src[8 * j];
        #pragma unroll
        for (int j = 0; j < 8; ++j) {
            short4 s;
            s.x = f2bf(sv[j].x); s.y = f2bf(sv[j].y);
            s.z = f2bf(sv[j].z); s.w = f2bf(sv[j].w);
            *(short4*)((char*)A_lds + SWZ(srow, srow * (DT_ * 2) + (sc + 8 * j) * 8)) = s;
        }
    }
    __syncthreads();

    f32x4 acc[5][4];
    #pragma unroll
    for (int ct = 0; ct < 5; ++ct)
        #pragma unroll
        for (int rt = 0; rt < 4; ++rt) acc[ct][rt] = (f32x4){0.f,0.f,0.f,0.f};

    const short* Wbase = Wb + (long)(w * 80 + r16) * DT_ + g * 8;

    bf16x8 aA[4], bA[5], aB[4], bB[5];
    #pragma unroll
    for (int rt = 0; rt < 4; ++rt) {
        const int row = rt * 16 + r16;
        aA[rt] = *(const bf16x8*)((const char*)A_lds + SWZ(row, row * (DT_ * 2) + g * 16));
    }
    #pragma unroll
    for (int ct = 0; ct < 5; ++ct) bA[ct] = *(const bf16x8*)(Wbase + ct * 16 * DT_);

    #pragma unroll
    for (int kc = 0; kc < 8; kc += 2) {
        {
            const int kn = kc + 1;
            #pragma unroll
            for (int rt = 0; rt < 4; ++rt) {
                const int row = rt * 16 + r16;
                aB[rt] = *(const bf16x8*)((const char*)A_lds +
                          SWZ(row, row * (DT_ * 2) + kn * 64 + g * 16));
            }
            #pragma unroll
            for (int ct = 0; ct < 5; ++ct)
                bB[ct] = *(const bf16x8*)(Wbase + ct * 16 * DT_ + kn * 32);
        }
        #pragma unroll
        for (int ct = 0; ct < 5; ++ct)
            #pragma unroll
            for (int rt = 0; rt < 4; ++rt)
                acc[ct][rt] = __builtin_amdgcn_mfma_f32_16x16x32_bf16(
                                  aA[rt], bA[ct], acc[ct][rt], 0, 0, 0);
        {
            const int kn = (kc + 2 < 8) ? kc + 2 : 0;
            #pragma unroll
            for (int rt = 0; rt < 4; ++rt) {
                const int row = rt * 16 + r16;
                aA[rt] = *(const bf16x8*)((const char*)A_lds +
                          SWZ(row, row * (DT_ * 2) + kn * 64 + g * 16));
            }
            #pragma unroll
            for (int ct = 0; ct < 5; ++ct)
                bA[ct] = *(const bf16x8*)(Wbase + ct * 16 * DT_ + kn * 32);
        }
        #pragma unroll
        for (int ct = 0; ct < 5; ++ct)
            #pragma unroll
            for (int rt = 0; rt < 4; ++rt)
                acc[ct][rt] = __builtin_amdgcn_mfma_f32_16x16x32_bf16(
                                  aB[rt], bB[ct], acc[ct][rt], 0, 0, 0);
    }

    #pragma unroll
    for (int ct = 0; ct < 5; ++ct) {
        const int col = w * 80 + ct * 16 + r16;
        const float bv = bias[col];
        #pragma unroll
        for (int rt = 0; rt < 4; ++rt)
            #pragma unroll
            for (int i = 0; i < 4; ++i)
                Y[(row0 + rt * 16 + g * 4 + i) * (long)D_ + col] =
                    f2bf(acc[ct][rt][i] + bv);
    }
}

// Fused attention + aggregation, one batch b per block.
__global__ __launch_bounds__(512, 2) void attn2(
    const short* __restrict__ Qb, const short* __restrict__ Kb,
    float* __restrict__ aw, float* __restrict__ out_tail)
{
    __shared__ float qn_l[N_];
    __shared__ float qw_l[N_];
    __shared__ float aggp[8][MT_ * 16];
    __shared__ float red2[2];
    const int t = threadIdx.x;
    const int lane = t & 63, w = t >> 6;
    const int wm = w & 3, hh = w >> 2;
    const int r16 = lane & 15, g = lane >> 4;
    const int b = blockIdx.x;

    if (hh == 0) {
        const short* qrow = Qb + ((long)(b * N_ + wm * 16 + r16)) * D_ + g * 160;
        float ss = 0.f;
        #pragma unroll
        for (int j = 0; j < 20; ++j) {
            bf16x8 v = *(const bf16x8*)(qrow + j * 8);
            #pragma unroll
            for (int e = 0; e < 8; ++e) { float f = bf2f(v[e]); ss += f * f; }
        }
        ss += __shfl_xor(ss, 16);
        ss += __shfl_xor(ss, 32);
        if (g == 0) qn_l[wm * 16 + r16] = ss;
    }
    __syncthreads();
    if (w == 0) {
        float v = sqrtf(qn_l[lane]);
        float mx = wave_reduce_max(v);
        float e = __expf(v - mx);
        float s = wave_reduce_sum(e);
        qw_l[lane] = e / s;
    }
    __syncthreads();

    float qwr[4];
    #pragma unroll
    for (int i = 0; i < 4; ++i) qwr[i] = qw_l[wm * 16 + g * 4 + i];

    const float inv_scale = 0.0395284707521047f;   // 1/sqrt(640)
    float aggl[MT_];
    #pragma unroll
    for (int mt = 0; mt < MT_; ++mt) aggl[mt] = 0.f;

    for (int hi = 0; hi < 5; ++hi) {
        const int h = hh * 5 + hi;
        const short* qbase = Qb + ((long)(b * N_ + wm * 16 + r16)) * D_ + h * HD_ + g * 8;
        bf16x8 a0 = *(const bf16x8*)(qbase);
        bf16x8 a1 = *(const bf16x8*)(qbase + 32);
        bf16x8 kb0[MT_], kb1[MT_];
        #pragma unroll
        for (int mt = 0; mt < MT_; ++mt) {
            const short* kbase = Kb + ((long)(b * H_ + mt * 16 + r16)) * D_ + h * HD_ + g * 8;
            kb0[mt] = *(const bf16x8*)(kbase);
            kb1[mt] = *(const bf16x8*)(kbase + 32);
        }
        f32x4 acc[MT_];
        #pragma unroll
        for (int mt = 0; mt < MT_; ++mt) {
            f32x4 z = {0.f,0.f,0.f,0.f};
            z = __builtin_amdgcn_mfma_f32_16x16x32_bf16(a0, kb0[mt], z, 0, 0, 0);
            z = __builtin_amdgcn_mfma_f32_16x16x32_bf16(a1, kb1[mt], z, 0, 0, 0);
            acc[mt] = z;
        }
        const bool tailok = (r16 < 8);
        float mx[4] = {-INFINITY, -INFINITY, -INFINITY, -INFINITY};
        #pragma unroll
        for (int mt = 0; mt < MT_; ++mt) {
            const bool valid = (mt < 12) || tailok;
            #pragma unroll
            for (int i = 0; i < 4; ++i)
                if (valid) mx[i] = fmaxf(mx[i], acc[mt][i]);
        }
        #pragma unroll
        for (int i = 0; i < 4; ++i) mx[i] = red16_max(mx[i]);
        float sum[4] = {0.f, 0.f, 0.f, 0.f};
        #pragma unroll
        for (int mt = 0; mt < MT_; ++mt) {
            const bool valid = (mt < 12) || tailok;
            #pragma unroll
            for (int i = 0; i < 4; ++i) {
                float e = valid ? __expf((acc[mt][i] - mx[i]) * inv_scale) : 0.f;
                acc[mt][i] = e;
                sum[i] += e;
            }
        }
        float fct[4];
        #pragma unroll
        for (int i = 0; i < 4; ++i) fct[i] = qwr[i] / red16_sum(sum[i]);
        #pragma unroll
        for (int mt = 0; mt < MT_; ++mt)
            aggl[mt] += acc[mt][0] * fct[0] + acc[mt][1] * fct[1]
                      + acc[mt][2] * fct[2] + acc[mt][3] * fct[3];
    }
    #pragma unroll
    for (int mt = 0; mt < MT_; ++mt) {
        aggl[mt] += __shfl_xor(aggl[mt], 16);
        aggl[mt] += __shfl_xor(aggl[mt], 32);
    }
    if (g == 0) {
        #pragma unroll
        for (int mt = 0; mt < MT_; ++mt) aggp[w][mt * 16 + r16] = aggl[mt];
    }
    __syncthreads();
    if (t < MT_ * 16) {
        float v = 0.f;
        #pragma unroll
        for (int j = 0; j < 8; ++j) v += aggp[j][t];
        aggp[0][t] = v;
    }
    __syncthreads();
    if (w == 0) {
        float v0 = aggp[0][lane], v1 = aggp[0][lane + 64], v2 = aggp[0][lane + 128];
        const bool has3 = lane < (H_ - 192);
        float v3 = has3 ? aggp[0][lane + 192] : -INFINITY;
        float mx = wave_reduce_max(fmaxf(fmaxf(v0, v1), fmaxf(v2, v3)));
        float s = __expf(v0 - mx) + __expf(v1 - mx) + __expf(v2 - mx)
                + (has3 ? __expf(v3 - mx) : 0.f);
        s = wave_reduce_sum(s);
        if (lane == 0) { red2[0] = mx; red2[1] = s; }
    }
    __syncthreads();
    if (t < H_) {
        float v = __expf(aggp[0][t] - red2[0]) / red2[1];
        aw[b * H_ + t] = v;
        out_tail[b * H_ + t] = v;
    }
}

// gate GEMM + blend + LayerNorm, v5: 2-phase pipelined streaming GEMM.
// BM=64, 512 threads = 8 waves. W double-buffered in LDS (chunk KC=32),
// stage of chunk k+1 ISSUED BEFORE compute of chunk k; ONE barrier per chunk.
// A (unscaled clicked bf16) full-resident in LDS, staged chunk-wise with a
// 1-deep register prefetch. LDS = exactly 160 KB -> LN partials go through
// a small global scratch (part_g).
__global__ __launch_bounds__(512, 2) void out_mfma(
    const float* __restrict__ clicked, const float* __restrict__ aw,
    const short* __restrict__ Wgb, const float* __restrict__ bg,
    const float* __restrict__ gamma, const float* __restrict__ beta,
    float* __restrict__ out, float* __restrict__ part_g)
{
    __shared__ short A_lds[64 * D_];        // 80 KB
    __shared__ short W_lds[2][D_ * 32];     // 80 KB (2 x 40 KB)
    const int t = threadIdx.x;
    const int lane = t & 63, w = t >> 6;
    const int r16 = lane & 15, g = lane >> 4;
    const int bid = blockIdx.x;
    const long row0 = (long)bid * 64;

    // per-thread epilogue params (cols w*80 + ct*16 + r16)
    float bgr[5], gmr[5], btr[5];
    #pragma unroll
    for (int ct = 0; ct < 5; ++ct) {
        const int col = w * 80 + ct * 16 + r16;
        bgr[ct] = bg[col]; gmr[ct] = gamma[col]; btr[ct] = beta[col];
    }

    // A staging: thread -> (row = t>>3, seg = t&7); 1 float4 (4 floats) per chunk
    const int arow = t >> 3, aseg = t & 7;
    const float* Asrc = clicked + (row0 + arow) * D_ + aseg * 4;

    f32x4 acc[5][4];
    #pragma unroll
    for (int ct = 0; ct < 5; ++ct)
        #pragma unroll
        for (int rt = 0; rt < 4; ++rt) acc[ct][rt] = (f32x4){0.f,0.f,0.f,0.f};

    // ---- prologue: A chunk0 staged, W chunk0 staged, A chunk1 in regs ----
    float4 av = *(const float4*)(Asrc);         // chunk 0
    {
        const short* wsrc = Wgb;                 // chunk 0 (pre-swizzled)
        #pragma unroll
        for (int j = 0; j < 5; ++j) {
            const int u = t + j * 512;
            gload_lds16(wsrc + u * 8, (char*)W_lds[0] + u * 16);
        }
    }
    {
        short4 s;
        s.x = f2bf(av.x); s.y = f2bf(av.y); s.z = f2bf(av.z); s.w = f2bf(av.w);
        *(short4*)((char*)A_lds + SWZ(arow, arow * (D_ * 2) + 0 * 64 + aseg * 8)) = s;
    }
    av = *(const float4*)(Asrc + 32);           // chunk 1
    __syncthreads();

    // ---- main loop: ONE barrier per chunk; stage k+1 issued before compute k
    int cur = 0;
    for (int k = 0; k < 20; ++k) {
        const int nxt = cur ^ 1;
        if (k + 1 < 20) {
            const short* wsrc = Wgb + (long)(k + 1) * (D_ * 32);
            #pragma unroll
            for (int j = 0; j < 5; ++j) {
                const int u = t + j * 512;
                gload_lds16(wsrc + u * 8, (char*)W_lds[nxt] + u * 16);
            }
            short4 s;
            s.x = f2bf(av.x); s.y = f2bf(av.y); s.z = f2bf(av.z); s.w = f2bf(av.w);
            *(short4*)((char*)A_lds +
                SWZ(arow, arow * (D_ * 2) + (k + 1) * 64 + aseg * 8)) = s;
        }
        if (k + 2 < 20) av = *(const float4*)(Asrc + (k + 2) * 32);

        // compute chunk k
        bf16x8 a[4];
        #pragma unroll
        for (int rt = 0; rt < 4; ++rt) {
            const int row = rt * 16 + r16;
            a[rt] = *(const bf16x8*)((const char*)A_lds +
                     SWZ(row, row * (D_ * 2) + k * 64 + g * 16));
        }
        bf16x8 bb[5];
        #pragma unroll
        for (int ct = 0; ct < 5; ++ct) {
            const int c3 = w * 80 + ct * 16 + r16;
            bb[ct] = *(const bf16x8*)((const short*)W_lds[cur] +
                      WSWZ_S(c3, c3 * 32 + g * 8));
        }
        #pragma unroll
        for (int ct = 0; ct < 5; ++ct)
            #pragma unroll
            for (int rt = 0; rt < 4; ++rt)
                acc[ct][rt] = __builtin_amdgcn_mfma_f32_16x16x32_bf16(
                                  a[rt], bb[ct], acc[ct][rt], 0, 0, 0);
        __syncthreads();
        cur = nxt;
    }

    // ---- in-register epilogue: z = aw*y + bg; gate; o = cl*(1 + gt*(aw-1))
    float awv[4][4];
    #pragma unroll
    for (int rt = 0; rt < 4; ++rt)
        #pragma unroll
        for (int i = 0; i < 4; ++i)
            awv[rt][i] = aw[row0 + rt * 16 + g * 4 + i];

    float ps[4][4], pq[4][4];
    #pragma unroll
    for (int rt = 0; rt < 4; ++rt)
        #pragma unroll
        for (int i = 0; i < 4; ++i) { ps[rt][i] = 0.f; pq[rt][i] = 0.f; }

    #pragma unroll
    for (int ct = 0; ct < 5; ++ct) {
        const int col = w * 80 + ct * 16 + r16;
        #pragma unroll
        for (int rt = 0; rt < 4; ++rt)
            #pragma unroll
            for (int i = 0; i < 4; ++i) {
                const int row = rt * 16 + g * 4 + i;
                const float awr = awv[rt][i];
                const float cl = bf2f(*(const short*)((const char*)A_lds +
                                   SWZ(row, row * (D_ * 2) + col * 2)));
                const float z  = awr * acc[ct][rt][i] + bgr[ct];
                const float gt = 1.f / (1.f + __expf(-z));
                const float o  = cl * (1.f + gt * (awr - 1.f));
                acc[ct][rt][i] = o;
                ps[rt][i] += o; pq[rt][i] += o * o;
            }
    }
    // per-wave row partials -> global scratch (LDS is full)
    float* pg = part_g + (long)bid * 1280;
    #pragma unroll
    for (int rt = 0; rt < 4; ++rt)
        #pragma unroll
        for (int i = 0; i < 4; ++i) {
            const float s  = red16_sum(ps[rt][i]);
            const float sq = red16_sum(pq[rt][i]);
            if (r16 == 0) {
                const int row = rt * 16 + g * 4 + i;
                pg[(w * 64 + row) * 2 + 0] = s;
                pg[(w * 64 + row) * 2 + 1] = sq;
            }
        }
    __syncthreads();
    if (t < 64) {
        float s = 0.f, q = 0.f;
        #pragma unroll
        for (int j = 0; j < 8; ++j) {
            s += pg[(j * 64 + t) * 2 + 0];
            q += pg[(j * 64 + t) * 2 + 1];
        }
        const float m = s * (1.f / D_);
        const float v = q * (1.f / D_) - m * m;
        pg[1024 + t * 2 + 0] = m;
        pg[1024 + t * 2 + 1] = 1.0f / sqrtf(v + 1e-5f);
    }
    __syncthreads();

    #pragma unroll
    for (int rt = 0; rt < 4; ++rt)
        #pragma unroll
        for (int i = 0; i < 4; ++i) {
            const int row = rt * 16 + g * 4 + i;
            const float mu = pg[1024 + row * 2 + 0];
            const float ri = pg[1024 + row * 2 + 1];
            #pragma unroll
            for (int ct = 0; ct < 5; ++ct) {
                const int col = w * 80 + ct * 16 + r16;
                out[(row0 + row) * (long)D_ + col] =
                    (acc[ct][rt][i] - mu) * ri * gmr[ct] + btr[ct];
            }
        }
}

extern "C" void kernel_launch(void* const* d_in, const int* in_sizes, int n_in,
                              void* d_out, int out_size, void* d_ws, size_t ws_size,
                              hipStream_t stream) {
    const float* clicked_news   = (const float*)d_in[0];   // [B,H,D]
    const float* clicked_topics = (const float*)d_in[1];   // [B,H,Dt]
    const float* cand_topics    = (const float*)d_in[2];   // [B,N,Dt]
    const float* Wq = (const float*)d_in[3];
    const float* bq = (const float*)d_in[4];
    const float* Wk = (const float*)d_in[5];
    const float* bk = (const float*)d_in[6];
    // d_in[7], d_in[8] = Wv, bv: dead code w.r.t. outputs
    const float* Wg = (const float*)d_in[9];
    const float* bg = (const float*)d_in[10];
    const float* ln_gamma = (const float*)d_in[11];
    const float* ln_beta  = (const float*)d_in[12];

    float* out = (float*)d_out;
    float* ws  = (float*)d_ws;

    // ws layout: aw (f32), part_g (f32), then bf16 arrays
    float* aw     = ws;                                  // B*H floats
    float* part_g = aw + (long)B_ * H_;                  // 800*1280 floats
    short* sbase  = (short*)(part_g + (long)800 * 1280);
    short* Qb   = sbase;                                 // B*N*D shorts
    short* Wq_b = Qb + (long)B_ * N_ * D_;               // 163,840
    short* Wg_b = Wq_b + (long)D_ * DT_;                 // 409,600 (chunked+swz)
    short* Wk_b = Wg_b + (long)D_ * D_;                  // 163,840
    // Kb (bf16) at start of d_out: read by attn2, overwritten by out_mfma.
    short* Kb = (short*)d_out;
    float* out_tail = out + (long)B_ * H_ * D_;          // attn_weights_agg

    convert_w<<<128, 256, 0, stream>>>(Wq, Wq_b, D_ * DT_);
    convert_w<<<128, 256, 0, stream>>>(Wk, Wk_b, D_ * DT_);
    convert_wg<<<256, 256, 0, stream>>>(Wg, Wg_b);

    proj_mfma<<<(B_ * N_) / 64, 512, 0, stream>>>(cand_topics, Wq_b, bq, Qb);
    proj_mfma<<<(B_ * H_) / 64, 512, 0, stream>>>(clicked_topics, Wk_b, bk, Kb);
    attn2<<<B_, 512, 0, stream>>>(Qb, Kb, aw, out_tail);
    out_mfma<<<(B_ * H_) / 64, 512, 0, stream>>>(clicked_news, aw, Wg_b, bg,
                                                 ln_gamma, ln_beta, out, part_g);
}

// Round 10
// 295.829 us; speedup vs baseline: 1.1736x; 1.0118x over previous
//
#include <hip/hip_runtime.h>
#include <math.h>

#define B_  256
#define H_  200
#define N_  64
#define D_  640
#define DT_ 256
#define NH_ 10
#define HD_ 64
#define MT_ 13   // 13 m-tiles of 16 cover 208 >= 200

typedef __attribute__((ext_vector_type(8))) short bf16x8;
typedef __attribute__((ext_vector_type(4))) float f32x4;

__device__ __forceinline__ float wave_reduce_sum(float v) {
    #pragma unroll
    for (int m = 32; m > 0; m >>= 1) v += __shfl_xor(v, m);
    return v;
}
__device__ __forceinline__ float wave_reduce_max(float v) {
    #pragma unroll
    for (int m = 32; m > 0; m >>= 1) v = fmaxf(v, __shfl_xor(v, m));
    return v;
}
__device__ __forceinline__ float red16_sum(float v) {   // reduce over lane&15 group
    #pragma unroll
    for (int m = 1; m < 16; m <<= 1) v += __shfl_xor(v, m);
    return v;
}
__device__ __forceinline__ float red16_max(float v) {
    #pragma unroll
    for (int m = 1; m < 16; m <<= 1) v = fmaxf(v, __shfl_xor(v, m));
    return v;
}
__device__ __forceinline__ short f2bf(float x) {   // RNE bf16
    unsigned u = __float_as_uint(x);
    unsigned r = (u + 0x7fffu + ((u >> 16) & 1u)) >> 16;
    return (short)r;
}
__device__ __forceinline__ float bf2f(short s) {
    return __uint_as_float(((unsigned)(unsigned short)s) << 16);
}
// LDS XOR swizzle for bf16 A tiles (row stride mult of 128B)
#define SWZ(row, byte) ((byte) ^ (((row) & 7) << 4))
// W-chunk swizzle (col stride 64B): short-index XOR
#define WSWZ_S(col, sidx) ((sidx) ^ ((((col) >> 1) & 3) << 3))

__device__ __forceinline__ void gload_lds16(const void* g, void* lds) {
    __builtin_amdgcn_global_load_lds(
        (const __attribute__((address_space(1))) void*)g,
        (__attribute__((address_space(3))) void*)lds, 16, 0, 0);
}

__global__ __launch_bounds__(256) void convert_w(
    const float* __restrict__ src, short* __restrict__ dst, int n)
{
    for (int i = blockIdx.x * 256 + threadIdx.x; i < n; i += gridDim.x * 256)
        dst[i] = f2bf(src[i]);
}

// Gate weight -> bf16 in CHUNKED+PRE-SWIZZLED layout:
// dst[kc][ WSWZ_S(col, col*32+kk) ] = Wg[col][kc*32+kk]
__global__ __launch_bounds__(256) void convert_wg(
    const float* __restrict__ src, short* __restrict__ dst)
{
    for (int i = blockIdx.x * 256 + threadIdx.x; i < D_ * D_; i += gridDim.x * 256) {
        const int col = i / D_, k = i % D_;
        const int kc = k >> 5, kk = k & 31;
        dst[kc * (D_ * 32) + WSWZ_S(col, col * 32 + kk)] = f2bf(src[i]);
    }
}

// Y_bf16[row, d] = bf16( sum_k X[row,k]*W[d,k] + bias[d] );  K = DT_ = 256.
__global__ __launch_bounds__(512, 2) void proj_mfma(
    const float* __restrict__ X, const short* __restrict__ Wb,
    const float* __restrict__ bias, short* __restrict__ Y)
{
    __shared__ short A_lds[64 * DT_];   // 32 KB swizzled bf16
    const int t = threadIdx.x;
    const int lane = t & 63, w = t >> 6;
    const int r16 = lane & 15, g = lane >> 4;
    const long row0 = (long)blockIdx.x * 64;

    {
        const int srow = t >> 3, sc = t & 7;
        const float4* src = (const float4*)(X + (row0 + srow) * DT_) + sc;
        float4 sv[8];
        #pragma unroll
        for (int j = 0; j < 8; ++j) sv[j] = src[8 * j];
        #pragma unroll
        for (int j = 0; j < 8; ++j) {
            short4 s;
            s.x = f2bf(sv[j].x); s.y = f2bf(sv[j].y);
            s.z = f2bf(sv[j].z); s.w = f2bf(sv[j].w);
            *(short4*)((char*)A_lds + SWZ(srow, srow * (DT_ * 2) + (sc + 8 * j) * 8)) = s;
        }
    }
    __syncthreads();

    f32x4 acc[5][4];
    #pragma unroll
    for (int ct = 0; ct < 5; ++ct)
        #pragma unroll
        for (int rt = 0; rt < 4; ++rt) acc[ct][rt] = (f32x4){0.f,0.f,0.f,0.f};

    const short* Wbase = Wb + (long)(w * 80 + r16) * DT_ + g * 8;

    bf16x8 aA[4], bA[5], aB[4], bB[5];
    #pragma unroll
    for (int rt = 0; rt < 4; ++rt) {
        const int row = rt * 16 + r16;
        aA[rt] = *(const bf16x8*)((const char*)A_lds + SWZ(row, row * (DT_ * 2) + g * 16));
    }
    #pragma unroll
    for (int ct = 0; ct < 5; ++ct) bA[ct] = *(const bf16x8*)(Wbase + ct * 16 * DT_);

    #pragma unroll
    for (int kc = 0; kc < 8; kc += 2) {
        {
            const int kn = kc + 1;
            #pragma unroll
            for (int rt = 0; rt < 4; ++rt) {
                const int row = rt * 16 + r16;
                aB[rt] = *(const bf16x8*)((const char*)A_lds +
                          SWZ(row, row * (DT_ * 2) + kn * 64 + g * 16));
            }
            #pragma unroll
            for (int ct = 0; ct < 5; ++ct)
                bB[ct] = *(const bf16x8*)(Wbase + ct * 16 * DT_ + kn * 32);
        }
        #pragma unroll
        for (int ct = 0; ct < 5; ++ct)
            #pragma unroll
            for (int rt = 0; rt < 4; ++rt)
                acc[ct][rt] = __builtin_amdgcn_mfma_f32_16x16x32_bf16(
                                  aA[rt], bA[ct], acc[ct][rt], 0, 0, 0);
        {
            const int kn = (kc + 2 < 8) ? kc + 2 : 0;
            #pragma unroll
            for (int rt = 0; rt < 4; ++rt) {
                const int row = rt * 16 + r16;
                aA[rt] = *(const bf16x8*)((const char*)A_lds +
                          SWZ(row, row * (DT_ * 2) + kn * 64 + g * 16));
            }
            #pragma unroll
            for (int ct = 0; ct < 5; ++ct)
                bA[ct] = *(const bf16x8*)(Wbase + ct * 16 * DT_ + kn * 32);
        }
        #pragma unroll
        for (int ct = 0; ct < 5; ++ct)
            #pragma unroll
            for (int rt = 0; rt < 4; ++rt)
                acc[ct][rt] = __builtin_amdgcn_mfma_f32_16x16x32_bf16(
                                  aB[rt], bB[ct], acc[ct][rt], 0, 0, 0);
    }

    #pragma unroll
    for (int ct = 0; ct < 5; ++ct) {
        const int col = w * 80 + ct * 16 + r16;
        const float bv = bias[col];
        #pragma unroll
        for (int rt = 0; rt < 4; ++rt)
            #pragma unroll
            for (int i = 0; i < 4; ++i)
                Y[(row0 + rt * 16 + g * 4 + i) * (long)D_ + col] =
                    f2bf(acc[ct][rt][i] + bv);
    }
}

// Fused attention + aggregation, one batch b per block.
__global__ __launch_bounds__(512, 2) void attn2(
    const short* __restrict__ Qb, const short* __restrict__ Kb,
    float* __restrict__ aw, float* __restrict__ out_tail)
{
    __shared__ float qn_l[N_];
    __shared__ float qw_l[N_];
    __shared__ float aggp[8][MT_ * 16];
    __shared__ float red2[2];
    const int t = threadIdx.x;
    const int lane = t & 63, w = t >> 6;
    const int wm = w & 3, hh = w >> 2;
    const int r16 = lane & 15, g = lane >> 4;
    const int b = blockIdx.x;

    if (hh == 0) {
        const short* qrow = Qb + ((long)(b * N_ + wm * 16 + r16)) * D_ + g * 160;
        float ss = 0.f;
        #pragma unroll
        for (int j = 0; j < 20; ++j) {
            bf16x8 v = *(const bf16x8*)(qrow + j * 8);
            #pragma unroll
            for (int e = 0; e < 8; ++e) { float f = bf2f(v[e]); ss += f * f; }
        }
        ss += __shfl_xor(ss, 16);
        ss += __shfl_xor(ss, 32);
        if (g == 0) qn_l[wm * 16 + r16] = ss;
    }
    __syncthreads();
    if (w == 0) {
        float v = sqrtf(qn_l[lane]);
        float mx = wave_reduce_max(v);
        float e = __expf(v - mx);
        float s = wave_reduce_sum(e);
        qw_l[lane] = e / s;
    }
    __syncthreads();

    float qwr[4];
    #pragma unroll
    for (int i = 0; i < 4; ++i) qwr[i] = qw_l[wm * 16 + g * 4 + i];

    const float inv_scale = 0.0395284707521047f;   // 1/sqrt(640)
    float aggl[MT_];
    #pragma unroll
    for (int mt = 0; mt < MT_; ++mt) aggl[mt] = 0.f;

    for (int hi = 0; hi < 5; ++hi) {
        const int h = hh * 5 + hi;
        const short* qbase = Qb + ((long)(b * N_ + wm * 16 + r16)) * D_ + h * HD_ + g * 8;
        bf16x8 a0 = *(const bf16x8*)(qbase);
        bf16x8 a1 = *(const bf16x8*)(qbase + 32);
        bf16x8 kb0[MT_], kb1[MT_];
        #pragma unroll
        for (int mt = 0; mt < MT_; ++mt) {
            const short* kbase = Kb + ((long)(b * H_ + mt * 16 + r16)) * D_ + h * HD_ + g * 8;
            kb0[mt] = *(const bf16x8*)(kbase);
            kb1[mt] = *(const bf16x8*)(kbase + 32);
        }
        f32x4 acc[MT_];
        #pragma unroll
        for (int mt = 0; mt < MT_; ++mt) {
            f32x4 z = {0.f,0.f,0.f,0.f};
            z = __builtin_amdgcn_mfma_f32_16x16x32_bf16(a0, kb0[mt], z, 0, 0, 0);
            z = __builtin_amdgcn_mfma_f32_16x16x32_bf16(a1, kb1[mt], z, 0, 0, 0);
            acc[mt] = z;
        }
        const bool tailok = (r16 < 8);
        float mx[4] = {-INFINITY, -INFINITY, -INFINITY, -INFINITY};
        #pragma unroll
        for (int mt = 0; mt < MT_; ++mt) {
            const bool valid = (mt < 12) || tailok;
            #pragma unroll
            for (int i = 0; i < 4; ++i)
                if (valid) mx[i] = fmaxf(mx[i], acc[mt][i]);
        }
        #pragma unroll
        for (int i = 0; i < 4; ++i) mx[i] = red16_max(mx[i]);
        float sum[4] = {0.f, 0.f, 0.f, 0.f};
        #pragma unroll
        for (int mt = 0; mt < MT_; ++mt) {
            const bool valid = (mt < 12) || tailok;
            #pragma unroll
            for (int i = 0; i < 4; ++i) {
                float e = valid ? __expf((acc[mt][i] - mx[i]) * inv_scale) : 0.f;
                acc[mt][i] = e;
                sum[i] += e;
            }
        }
        float fct[4];
        #pragma unroll
        for (int i = 0; i < 4; ++i) fct[i] = qwr[i] / red16_sum(sum[i]);
        #pragma unroll
        for (int mt = 0; mt < MT_; ++mt)
            aggl[mt] += acc[mt][0] * fct[0] + acc[mt][1] * fct[1]
                      + acc[mt][2] * fct[2] + acc[mt][3] * fct[3];
    }
    #pragma unroll
    for (int mt = 0; mt < MT_; ++mt) {
        aggl[mt] += __shfl_xor(aggl[mt], 16);
        aggl[mt] += __shfl_xor(aggl[mt], 32);
    }
    if (g == 0) {
        #pragma unroll
        for (int mt = 0; mt < MT_; ++mt) aggp[w][mt * 16 + r16] = aggl[mt];
    }
    __syncthreads();
    if (t < MT_ * 16) {
        float v = 0.f;
        #pragma unroll
        for (int j = 0; j < 8; ++j) v += aggp[j][t];
        aggp[0][t] = v;
    }
    __syncthreads();
    if (w == 0) {
        float v0 = aggp[0][lane], v1 = aggp[0][lane + 64], v2 = aggp[0][lane + 128];
        const bool has3 = lane < (H_ - 192);
        float v3 = has3 ? aggp[0][lane + 192] : -INFINITY;
        float mx = wave_reduce_max(fmaxf(fmaxf(v0, v1), fmaxf(v2, v3)));
        float s = __expf(v0 - mx) + __expf(v1 - mx) + __expf(v2 - mx)
                + (has3 ? __expf(v3 - mx) : 0.f);
        s = wave_reduce_sum(s);
        if (lane == 0) { red2[0] = mx; red2[1] = s; }
    }
    __syncthreads();
    if (t < H_) {
        float v = __expf(aggp[0][t] - red2[0]) / red2[1];
        aw[b * H_ + t] = v;
        out_tail[b * H_ + t] = v;
    }
}

// gate GEMM + blend + LayerNorm, v6: TLP-first streaming GEMM.
// BM=32, BN=640, 512 threads = 8 waves; wave = 80 cols x 32 rows, acc[5][2].
// W single-buffered 40 KB (gload_lds from pre-swizzled Wg_b); A fp32 chunk
// double-buffered 2x4 KB, ALSO staged via gload_lds (per-lane inverse-swizzled
// global src, linear LDS dest), bf16-converted at frag-read time. LDS ~49 KB
// + __launch_bounds__(512,4) -> 2 blocks/CU: one block's barrier drain
// overlaps the other's compute. Two barriers per chunk (single W buffer).
// Epilogue: cl re-read from global (L3-hot); LN via part_g scratch.
__global__ __launch_bounds__(512, 4) void out_mfma(
    const float* __restrict__ clicked, const float* __restrict__ aw,
    const short* __restrict__ Wgb, const float* __restrict__ bg,
    const float* __restrict__ gamma, const float* __restrict__ beta,
    float* __restrict__ out, float* __restrict__ part_g)
{
    __shared__ short W_lds[D_ * 32];        // 40 KB, pre-swizzled layout
    __shared__ float Afp[2][32 * 32];       // 2 x 4 KB fp32 A chunks (swizzled)
    const int t = threadIdx.x;
    const int lane = t & 63, w = t >> 6;
    const int r16 = lane & 15, g = lane >> 4;
    const int bid = blockIdx.x;
    const long row0 = (long)bid * 32;

    f32x4 acc[5][2];
    #pragma unroll
    for (int ct = 0; ct < 5; ++ct) {
        acc[ct][0] = (f32x4){0.f,0.f,0.f,0.f};
        acc[ct][1] = (f32x4){0.f,0.f,0.f,0.f};
    }

    // ---- A chunk staging via gload_lds (t<256): slot u = row*8 + j covers
    // 16B; content = clicked row (row0+u>>3), floats k*32 + ((j^(row&7))*4..+3)
    // so that the read-side XOR swizzle ((g2h)^(row&7)) is bank-friendly.
    const int au_row = t >> 3, au_j = t & 7;
    const float* Ag = clicked + (row0 + au_row) * (long)D_ + ((au_j ^ (au_row & 7)) * 4);

    // prologue: stage A chunk 0
    if (t < 256) gload_lds16(Ag + 0 * 32, (char*)Afp[0] + t * 16);

    for (int k = 0; k < 20; ++k) {
        // stage W[k] (whole block) + A[k+1] (t<256)
        {
            const short* wsrc = Wgb + (long)k * (D_ * 32);
            #pragma unroll
            for (int j = 0; j < 5; ++j) {
                const int u = t + j * 512;
                gload_lds16(wsrc + u * 8, (char*)W_lds + u * 16);
            }
        }
        if (k + 1 < 20 && t < 256)
            gload_lds16(Ag + (k + 1) * 32, (char*)Afp[(k + 1) & 1] + t * 16);
        __syncthreads();   // drains W[k] + A[k+1] gloads; A[k] ready from prior iter

        // compute chunk k: convert A frags fp32->bf16, 10 MFMA
        const char* ab = (const char*)Afp[k & 1];
        bf16x8 a[2];
        #pragma unroll
        for (int rt = 0; rt < 2; ++rt) {
            const int row = rt * 16 + r16;
            float4 f0 = *(const float4*)(ab + row * 128 + (((g * 2 + 0) ^ (row & 7)) * 16));
            float4 f1 = *(const float4*)(ab + row * 128 + (((g * 2 + 1) ^ (row & 7)) * 16));
            bf16x8 av;
            av[0] = f2bf(f0.x); av[1] = f2bf(f0.y); av[2] = f2bf(f0.z); av[3] = f2bf(f0.w);
            av[4] = f2bf(f1.x); av[5] = f2bf(f1.y); av[6] = f2bf(f1.z); av[7] = f2bf(f1.w);
            a[rt] = av;
        }
        #pragma unroll
        for (int ct = 0; ct < 5; ++ct) {
            const int c3 = w * 80 + ct * 16 + r16;
            bf16x8 bb = *(const bf16x8*)((const short*)W_lds +
                         WSWZ_S(c3, c3 * 32 + g * 8));
            acc[ct][0] = __builtin_amdgcn_mfma_f32_16x16x32_bf16(a[0], bb, acc[ct][0], 0, 0, 0);
            acc[ct][1] = __builtin_amdgcn_mfma_f32_16x16x32_bf16(a[1], bb, acc[ct][1], 0, 0, 0);
        }
        __syncthreads();   // all waves done reading W[k] -> safe to overwrite
    }

    // ---- epilogue: z = aw*y + bg; gate; o = cl*(1 + gt*(aw-1)); LN ----
    float awv[2][4];
    #pragma unroll
    for (int rt = 0; rt < 2; ++rt)
        #pragma unroll
        for (int i = 0; i < 4; ++i)
            awv[rt][i] = aw[row0 + rt * 16 + g * 4 + i];

    float ps[2][4], pq[2][4];
    #pragma unroll
    for (int rt = 0; rt < 2; ++rt)
        #pragma unroll
        for (int i = 0; i < 4; ++i) { ps[rt][i] = 0.f; pq[rt][i] = 0.f; }

    #pragma unroll
    for (int ct = 0; ct < 5; ++ct) {
        const int col = w * 80 + ct * 16 + r16;
        const float bgv = bg[col];
        #pragma unroll
        for (int rt = 0; rt < 2; ++rt)
            #pragma unroll
            for (int i = 0; i < 4; ++i) {
                const int row = rt * 16 + g * 4 + i;
                const float awr = awv[rt][i];
                const float cl = clicked[(row0 + row) * (long)D_ + col];
                const float z  = awr * acc[ct][rt][i] + bgv;
                const float gt = 1.f / (1.f + __expf(-z));
                const float o  = cl * (1.f + gt * (awr - 1.f));
                acc[ct][rt][i] = o;
                ps[rt][i] += o; pq[rt][i] += o * o;
            }
    }
    float* pg = part_g + (long)bid * 640;
    #pragma unroll
    for (int rt = 0; rt < 2; ++rt)
        #pragma unroll
        for (int i = 0; i < 4; ++i) {
            const float s  = red16_sum(ps[rt][i]);
            const float sq = red16_sum(pq[rt][i]);
            if (r16 == 0) {
                const int row = rt * 16 + g * 4 + i;
                pg[(w * 32 + row) * 2 + 0] = s;
                pg[(w * 32 + row) * 2 + 1] = sq;
            }
        }
    __syncthreads();
    if (t < 32) {
        float s = 0.f, q = 0.f;
        #pragma unroll
        for (int j = 0; j < 8; ++j) {
            s += pg[(j * 32 + t) * 2 + 0];
            q += pg[(j * 32 + t) * 2 + 1];
        }
        const float m = s * (1.f / D_);
        const float v = q * (1.f / D_) - m * m;
        pg[512 + t * 2 + 0] = m;
        pg[512 + t * 2 + 1] = 1.0f / sqrtf(v + 1e-5f);
    }
    __syncthreads();

    #pragma unroll
    for (int rt = 0; rt < 2; ++rt)
        #pragma unroll
        for (int i = 0; i < 4; ++i) {
            const int row = rt * 16 + g * 4 + i;
            const float mu = pg[512 + row * 2 + 0];
            const float ri = pg[512 + row * 2 + 1];
            #pragma unroll
            for (int ct = 0; ct < 5; ++ct) {
                const int col = w * 80 + ct * 16 + r16;
                out[(row0 + row) * (long)D_ + col] =
                    (acc[ct][rt][i] - mu) * ri * gamma[col] + beta[col];
            }
        }
}

extern "C" void kernel_launch(void* const* d_in, const int* in_sizes, int n_in,
                              void* d_out, int out_size, void* d_ws, size_t ws_size,
                              hipStream_t stream) {
    const float* clicked_news   = (const float*)d_in[0];   // [B,H,D]
    const float* clicked_topics = (const float*)d_in[1];   // [B,H,Dt]
    const float* cand_topics    = (const float*)d_in[2];   // [B,N,Dt]
    const float* Wq = (const float*)d_in[3];
    const float* bq = (const float*)d_in[4];
    const float* Wk = (const float*)d_in[5];
    const float* bk = (const float*)d_in[6];
    // d_in[7], d_in[8] = Wv, bv: dead code w.r.t. outputs
    const float* Wg = (const float*)d_in[9];
    const float* bg = (const float*)d_in[10];
    const float* ln_gamma = (const float*)d_in[11];
    const float* ln_beta  = (const float*)d_in[12];

    float* out = (float*)d_out;
    float* ws  = (float*)d_ws;

    // ws layout: aw (f32), part_g (f32), then bf16 arrays
    float* aw     = ws;                                  // B*H floats
    float* part_g = aw + (long)B_ * H_;                  // 1600*640 floats
    short* sbase  = (short*)(part_g + (long)1600 * 640);
    short* Qb   = sbase;                                 // B*N*D shorts
    short* Wq_b = Qb + (long)B_ * N_ * D_;               // 163,840
    short* Wg_b = Wq_b + (long)D_ * DT_;                 // 409,600 (chunked+swz)
    short* Wk_b = Wg_b + (long)D_ * D_;                  // 163,840
    // Kb (bf16) at start of d_out: read by attn2, overwritten by out_mfma.
    short* Kb = (short*)d_out;
    float* out_tail = out + (long)B_ * H_ * D_;          // attn_weights_agg

    convert_w<<<128, 256, 0, stream>>>(Wq, Wq_b, D_ * DT_);
    convert_w<<<128, 256, 0, stream>>>(Wk, Wk_b, D_ * DT_);
    convert_wg<<<256, 256, 0, stream>>>(Wg, Wg_b);

    proj_mfma<<<(B_ * N_) / 64, 512, 0, stream>>>(cand_topics, Wq_b, bq, Qb);
    proj_mfma<<<(B_ * H_) / 64, 512, 0, stream>>>(clicked_topics, Wk_b, bk, Kb);
    attn2<<<B_, 512, 0, stream>>>(Qb, Kb, aw, out_tail);
    out_mfma<<<(B_ * H_) / 32, 512, 0, stream>>>(clicked_news, aw, Wg_b, bg,
                                                 ln_gamma, ln_beta, out, part_g);
}